// Round 9
// baseline (191.822 us; speedup 1.0000x reference)
//
#include <hip/hip_runtime.h>

typedef __attribute__((ext_vector_type(8))) short short8;
typedef __attribute__((ext_vector_type(4))) float f32x4;

#define BB 64
#define TS 2000
#define NN (TS*160)
#define MB 48
#define TB 42            // tiles per batch row
#define NT (TB*BB)       // 2688 tiles total
#define GRID 256         // persistent: one block per CU
#define NTH 640          // 10 waves: wave = output col-tile ct
#define EPS_LOG 1.52587890625e-05f   // 2^-16

// ws layout: ushort (bf16) region then float region
#define W1F_U 0          // 40960 ushorts: [tap][ct10][kp16][col16][8]
#define W1T_U 40960      // 20480 ushorts: [tap][ct10][kp8][col16][8] (k>=41 zero)
#define W2_U  61440      // 51200 ushorts: [tap][ct10][kp20][col16][8]
#define B1C_F 56320      // float idx: b1f+b1t (160)
#define B2C_F 56480      // float idx: b2 (160)

__device__ __forceinline__ unsigned short f2bf(float f) {
    union { float f; unsigned u; } v; v.f = f;
    unsigned r = v.u + 0x7FFF + ((v.u >> 16) & 1);   // RNE
    return (unsigned short)(r >> 16);
}

__global__ void repack(const float* __restrict__ W1f, const float* __restrict__ b1f,
                       const float* __restrict__ W1t, const float* __restrict__ b1t,
                       const float* __restrict__ W2,  const float* __restrict__ b2,
                       void* wsv) {
    unsigned short* wu = (unsigned short*)wsv;
    float* wf = (float*)wsv;
    int n = blockIdx.x * 256 + threadIdx.x;
    if (n < 40960) {                       // W1f
        int tap = n / 20480, m = n % 20480;
        int ct = m / 2048, m2 = m % 2048;
        int kp = m2 / 128, col = (m2 % 128) / 8, i = m2 % 8;
        int o = ct * 16 + col, c = kp * 8 + i;
        wu[W1F_U + n] = f2bf(W1f[(o * 128 + c) * 2 + tap]);
    } else if (n < 61440) {                // W1t (K padded to 64)
        int r = n - 40960;
        int tap = r / 10240, m = r % 10240;
        int ct = m / 1024, m2 = m % 1024;
        int kp = m2 / 128, col = (m2 % 128) / 8, i = m2 % 8;
        int o = ct * 16 + col, c = kp * 8 + i;
        wu[W1T_U + r] = (c < 41) ? f2bf(W1t[(o * 41 + c) * 2 + tap]) : (unsigned short)0;
    } else if (n < 112640) {               // W2
        int r = n - 61440;
        int tap = r / 25600, m = r % 25600;
        int ct = m / 2560, m2 = m % 2560;
        int kp = m2 / 128, col = (m2 % 128) / 8, i = m2 % 8;
        int o = ct * 16 + col, c = kp * 8 + i;
        wu[W2_U + r] = f2bf(W2[(o * 160 + c) * 2 + tap]);
    } else if (n < 112800) {               // b1 combined
        int o = n - 112640;
        wf[B1C_F + o] = b1f[o] + b1t[o];
    } else if (n < 112960) {               // b2 copy
        int o = n - 112800;
        wf[B2C_F + o] = b2[o];
    }
}

__global__ __launch_bounds__(NTH) void td_main(
    const float* __restrict__ x,
    const float* __restrict__ feat,
    const unsigned short* __restrict__ wu,
    const float* __restrict__ wf,
    float* __restrict__ out)
{
    // r7 proven layout: strides ≡ 16B mod 128B on row-varying b128 reads
    __shared__ __align__(16) unsigned short s_feat[65 * 136]; // row r <-> t = t0-17+r
    __shared__ __align__(16) unsigned short s_tenv[65 * 72];  // cols 0..40 data, 41..63 zero
    __shared__ __align__(16) unsigned short s_hid [64 * 168]; // row h <-> t = t0-16+h
    float* s_e = (float*)s_hid;   // raw e-values [65][44] (11.4KB), alias: dead window of s_hid

    const int tid  = threadIdx.x;
    const int blk  = blockIdx.x;
    const int wid  = tid >> 6;    // 0..9 = ct (wave-stationary output col-tile)
    const int lane = tid & 63;
    const int lr   = lane & 15;   // A row within tile / D col
    const int lk   = lane >> 4;   // k-group / D row-group
    const int ct   = wid;

    // ---- weight prologue: register/AGPR-stationary for the whole persistent block ----
    short8 wB0[6], wB1[6];   // stage B: s=0..3 feat-taps, s=4..5 tenv-taps
    {
        const unsigned short* bf0 = wu + W1F_U + ct * 2048 + lk * 128 + lr * 8;
        const unsigned short* bt0 = wu + W1T_U + ct * 1024 + lk * 128 + lr * 8;
#pragma unroll
        for (int s = 0; s < 4; ++s) {
            wB0[s] = *(const short8*)(bf0 + s * 512);
            wB1[s] = *(const short8*)(bf0 + 20480 + s * 512);
        }
#pragma unroll
        for (int s = 0; s < 2; ++s) {
            wB0[4 + s] = *(const short8*)(bt0 + s * 512);
            wB1[4 + s] = *(const short8*)(bt0 + 10240 + s * 512);
        }
    }
    short8 wC0[5], wC1[5];
    {
        const unsigned short* b2p = wu + W2_U + ct * 2560 + lk * 128 + lr * 8;
#pragma unroll
        for (int s = 0; s < 5; ++s) {
            wC0[s] = *(const short8*)(b2p + s * 512);
            wC1[s] = *(const short8*)(b2p + 25600 + s * 512);
        }
    }
    const float bias1 = wf[B1C_F + ct * 16 + lr];
    const float bias2 = wf[B2C_F + ct * 16 + lr];

    const f32x4* feat4 = (const f32x4*)feat;
    const f32x4* x4    = (const f32x4*)x;

    float4 pf_f[4];   // prefetched feat (65*32 float4 / 640 thr)
    float4 pf_x[5];   // prefetched x pool-groups (65*40 float4 / 640 thr)

    // prefetch tile tau: issue predicated loads into registers
    auto PREFETCH = [&](int tau) {
        int bb = tau / TB, tb = tau - bb * TB, t0 = tb * MB;
#pragma unroll
        for (int i = 0; i < 4; ++i) {
            int idx = tid + i * NTH;
            int r = idx >> 5, c4 = idx & 31;
            int t = t0 - 17 + r;
            float4 v = make_float4(0.f, 0.f, 0.f, 0.f);
            if (idx < 65 * 32 && t >= 0 && t < TS) {
                f32x4 w = feat4[((size_t)bb * TS + t) * 32 + c4];
                v = make_float4(w.x, w.y, w.z, w.w);
            }
            pf_f[i] = v;
        }
#pragma unroll
        for (int i = 0; i < 5; ++i) {
            int idx = tid + i * NTH;
            int r = idx / 40, g = idx - r * 40;
            int t = t0 - 17 + r;
            float4 v = make_float4(0.f, 0.f, 0.f, 0.f);
            if (idx < 65 * 40 && t >= 0 && t < TS) {
                f32x4 w = x4[(size_t)bb * (NN / 4) + t * 40 + g];
                v = make_float4(w.x, w.y, w.z, w.w);
            }
            pf_x[i] = v;
        }
    };

    PREFETCH(blk);   // first tile

    for (int tau = blk; tau < NT; tau += GRID) {
        const int cb = tau / TB;
        const int t0 = (tau - cb * TB) * MB;

        __syncthreads();   // TOP: drains vmcnt -> prefetched regs + prev-iter C done

        // ---- stage feat regs -> bf16 LDS ----
#pragma unroll
        for (int i = 0; i < 4; ++i) {
            int idx = tid + i * NTH;
            if (idx < 65 * 32) {
                int r = idx >> 5, c4 = idx & 31;
                ushort4 h;
                h.x = f2bf(pf_f[i].x); h.y = f2bf(pf_f[i].y);
                h.z = f2bf(pf_f[i].z); h.w = f2bf(pf_f[i].w);
                *(ushort4*)&s_feat[r * 136 + c4 * 4] = h;
            }
        }
        // ---- per-group envelope e from x regs -> raw f32 LDS ----
#pragma unroll
        for (int i = 0; i < 5; ++i) {
            int idx = tid + i * NTH;
            if (idx < 65 * 40) {
                int r = idx / 40, g = idx - r * 40;
                float m = 0.25f * (fabsf(pf_x[i].x) + fabsf(pf_x[i].y)
                                 + fabsf(pf_x[i].z) + fabsf(pf_x[i].w));
                s_e[r * 44 + g] = __logf(m + EPS_LOG);
            }
        }
        __syncthreads();   // bar-A: e-values visible

        // ---- row mean + tenv write (half-wave per row) ----
        {
            const int hw = tid >> 5;     // 0..19
            const int hl = tid & 31;
            for (int r = hw; r < 65; r += NTH / 32) {
                int t = t0 - 17 + r;
                if (t >= 0 && t < TS) {
                    float e1 = s_e[r * 44 + hl];
                    float e2 = (hl < 8) ? s_e[r * 44 + 32 + hl] : 0.f;
                    float s = e1 + e2;
#pragma unroll
                    for (int m = 16; m; m >>= 1) s += __shfl_xor(s, m, 32);
                    float avg = s * 0.025f;
                    s_tenv[r * 72 + hl] = f2bf(e1 - avg);
                    if (hl < 8)        s_tenv[r * 72 + 32 + hl] = f2bf(e2 - avg);
                    else if (hl == 8)  s_tenv[r * 72 + 40]      = f2bf(avg);
                    else               s_tenv[r * 72 + 32 + hl] = 0;
                } else {
                    s_tenv[r * 72 + hl]      = 0;
                    s_tenv[r * 72 + 32 + hl] = 0;
                }
            }
        }
        __syncthreads();   // bar-MID: feat/tenv staged; s_e reads done

        const int cbase = lk * 8;

        // ===== stage B: hid = leaky(conv1f+conv1t); 4 time tiles =====
#pragma unroll 2
        for (int tile = 0; tile < 4; ++tile) {
            const int h0 = tile * 16;
            const unsigned short* f0 = &s_feat[(h0 + lr) * 136 + cbase];
            const unsigned short* e0 = &s_tenv[(h0 + lr) * 72 + cbase];
            f32x4 acc0 = {0.f, 0.f, 0.f, 0.f};
            f32x4 acc1 = {0.f, 0.f, 0.f, 0.f};
#pragma unroll
            for (int s = 0; s < 4; ++s) {
                short8 a0 = *(const short8*)(f0 + 32 * s);          // feat[t-1]
                short8 a1 = *(const short8*)(f0 + 136 + 32 * s);    // feat[t]
                acc0 = __builtin_amdgcn_mfma_f32_16x16x32_bf16(a0, wB0[s], acc0, 0, 0, 0);
                acc1 = __builtin_amdgcn_mfma_f32_16x16x32_bf16(a1, wB1[s], acc1, 0, 0, 0);
            }
#pragma unroll
            for (int s = 0; s < 2; ++s) {
                short8 a0 = *(const short8*)(e0 + 32 * s);
                short8 a1 = *(const short8*)(e0 + 72 + 32 * s);
                acc0 = __builtin_amdgcn_mfma_f32_16x16x32_bf16(a0, wB0[4 + s], acc0, 0, 0, 0);
                acc1 = __builtin_amdgcn_mfma_f32_16x16x32_bf16(a1, wB1[4 + s], acc1, 0, 0, 0);
            }
#pragma unroll
            for (int j = 0; j < 4; ++j) {
                int h  = h0 + lk * 4 + j;
                int th = t0 - 16 + h;
                float v = acc0[j] + acc1[j] + bias1;
                v = v >= 0.f ? v : 0.2f * v;
                s_hid[h * 168 + ct * 16 + lr] = (th >= 0) ? f2bf(v) : (unsigned short)0;
            }
        }
        __syncthreads();   // bar-2: hid ready

        // ---- T14: issue next tile's loads; they drain during stage C ----
        int taun = tau + GRID;
        if (taun < NT) PREFETCH(taun);

        // ===== stage C: out = exp(conv2(hid)+b2)*x; 3 time tiles =====
#pragma unroll
        for (int tile = 0; tile < 3; ++tile) {
            const unsigned short* hb = &s_hid[(15 + tile * 16 + lr) * 168 + cbase];
            f32x4 acc0 = {0.f, 0.f, 0.f, 0.f};
            f32x4 acc1 = {0.f, 0.f, 0.f, 0.f};
#pragma unroll
            for (int s = 0; s < 5; ++s) {
                short8 a0 = *(const short8*)(hb + 32 * s);          // hid[t-1]
                short8 a1 = *(const short8*)(hb + 168 + 32 * s);    // hid[t]
                acc0 = __builtin_amdgcn_mfma_f32_16x16x32_bf16(a0, wC0[s], acc0, 0, 0, 0);
                acc1 = __builtin_amdgcn_mfma_f32_16x16x32_bf16(a1, wC1[s], acc1, 0, 0, 0);
            }
#pragma unroll
            for (int j = 0; j < 4; ++j) {
                int t = t0 + tile * 16 + lk * 4 + j;
                if (t < TS) {
                    size_t off = (size_t)cb * NN + (size_t)t * 160 + ct * 16 + lr;
                    out[off] = __expf(acc0[j] + acc1[j] + bias2) * x[off];
                }
            }
        }
    }
}

extern "C" void kernel_launch(void* const* d_in, const int* in_sizes, int n_in,
                              void* d_out, int out_size, void* d_ws, size_t ws_size,
                              hipStream_t stream) {
    const float* x    = (const float*)d_in[0];
    const float* feat = (const float*)d_in[1];
    const float* W1f  = (const float*)d_in[2];
    const float* b1f  = (const float*)d_in[3];
    const float* W1t  = (const float*)d_in[4];
    const float* b1t  = (const float*)d_in[5];
    const float* W2   = (const float*)d_in[6];
    const float* b2   = (const float*)d_in[7];
    float* out = (float*)d_out;

    repack<<<(112960 + 255) / 256, 256, 0, stream>>>(W1f, b1f, W1t, b1t, W2, b2, d_ws);
    td_main<<<dim3(GRID), NTH, 0, stream>>>(
        x, feat, (const unsigned short*)d_ws, (const float*)d_ws, out);
}

// Round 10
// 174.460 us; speedup vs baseline: 1.0995x; 1.0995x over previous
//
#include <hip/hip_runtime.h>

typedef __attribute__((ext_vector_type(8))) short short8;
typedef __attribute__((ext_vector_type(4))) float f32x4;

#define BB 64
#define TS 2000
#define NN (TS*160)
#define MB 48
#define TB 42            // ceil(2000/48)
#define NTH 320          // 5 waves; wave handles ct = wid and wid+5
#define EPS_LOG 1.52587890625e-05f   // 2^-16

// ws layout: ushort (bf16) region then float region
#define W1F_U 0          // 40960 ushorts: [tap][ct10][kp16][col16][8]
#define W1T_U 40960      // 20480 ushorts: [tap][ct10][kp8][col16][8]  (MEAN-FOLDED W1teff; k>=40 zero)
#define W2_U  61440      // 51200 ushorts: [tap][ct10][kp20][col16][8]
#define B1C_F 56320      // float idx: b1f+b1t (160)
#define B2C_F 56480      // float idx: b2 (160)

__device__ __forceinline__ unsigned short f2bf(float f) {
    union { float f; unsigned u; } v; v.f = f;
    unsigned r = v.u + 0x7FFF + ((v.u >> 16) & 1);   // RNE
    return (unsigned short)(r >> 16);
}

__global__ void repack(const float* __restrict__ W1f, const float* __restrict__ b1f,
                       const float* __restrict__ W1t, const float* __restrict__ b1t,
                       const float* __restrict__ W2,  const float* __restrict__ b2,
                       void* wsv) {
    unsigned short* wu = (unsigned short*)wsv;
    float* wf = (float*)wsv;
    int n = blockIdx.x * 256 + threadIdx.x;
    if (n < 40960) {                       // W1f
        int tap = n / 20480, m = n % 20480;
        int ct = m / 2048, m2 = m % 2048;
        int kp = m2 / 128, col = (m2 % 128) / 8, i = m2 % 8;
        int o = ct * 16 + col, c = kp * 8 + i;
        wu[W1F_U + n] = f2bf(W1f[(o * 128 + c) * 2 + tap]);
    } else if (n < 61440) {                // W1teff: mean-folded, K padded to 64
        int r = n - 40960;
        int tap = r / 10240, m = r % 10240;
        int ct = m / 1024, m2 = m % 1024;
        int kp = m2 / 128, col = (m2 % 128) / 8, i = m2 % 8;
        int o = ct * 16 + col, c = kp * 8 + i;
        unsigned short v = 0;
        if (c < 40) {
            float S = 0.f;
            for (int g = 0; g < 40; ++g) S += W1t[(o * 41 + g) * 2 + tap];
            float w40 = W1t[(o * 41 + 40) * 2 + tap];
            v = f2bf(W1t[(o * 41 + c) * 2 + tap] + (w40 - S) * 0.025f);
        }
        wu[W1T_U + r] = v;
    } else if (n < 112640) {               // W2
        int r = n - 61440;
        int tap = r / 25600, m = r % 25600;
        int ct = m / 2560, m2 = m % 2560;
        int kp = m2 / 128, col = (m2 % 128) / 8, i = m2 % 8;
        int o = ct * 16 + col, c = kp * 8 + i;
        wu[W2_U + r] = f2bf(W2[(o * 160 + c) * 2 + tap]);
    } else if (n < 112800) {               // b1 combined
        int o = n - 112640;
        wf[B1C_F + o] = b1f[o] + b1t[o];
    } else if (n < 112960) {               // b2 copy
        int o = n - 112800;
        wf[B2C_F + o] = b2[o];
    }
}

__global__ __launch_bounds__(NTH) void td_main(
    const float* __restrict__ x,
    const float* __restrict__ feat,
    const unsigned short* __restrict__ wu,
    const float* __restrict__ wf,
    float* __restrict__ out)
{
    // r7-proven strides (row stride ≡ 16B mod 128B on row-varying b128 reads)
    __shared__ __align__(16) unsigned short s_feat[65 * 136]; // row r <-> t = t0-17+r
    __shared__ __align__(16) unsigned short s_e   [65 * 72];  // cols 0..39 = e, 40..63 zero
    __shared__ __align__(16) unsigned short s_hid [64 * 168]; // row h <-> t = t0-16+h

    const int tid  = threadIdx.x;
    const int b    = blockIdx.y;
    const int t0   = blockIdx.x * MB;
    const int wid  = tid >> 6;    // 0..4
    const int lane = tid & 63;
    const int lr   = lane & 15;   // A row within tile / D col
    const int lk   = lane >> 4;   // k-group / D row-group
    const int cbase = lk * 8;

    const float4* feat4 = (const float4*)feat;
    const float4* x4    = (const float4*)x;

    // ---- stage features -> bf16 LDS ----
    for (int idx = tid; idx < 65 * 32; idx += NTH) {
        int r = idx >> 5, c4 = idx & 31;
        int t = t0 - 17 + r;
        float4 v = make_float4(0.f, 0.f, 0.f, 0.f);
        if (t >= 0 && t < TS) v = feat4[((size_t)b * TS + t) * 32 + c4];
        ushort4 h;
        h.x = f2bf(v.x); h.y = f2bf(v.y); h.z = f2bf(v.z); h.w = f2bf(v.w);
        *(ushort4*)&s_feat[r * 136 + c4 * 4] = h;
    }
    // ---- stage e single-pass (mean folded into weights -> no reduce) ----
    for (int idx = tid; idx < 65 * 40; idx += NTH) {
        int r = idx / 40, g = idx - r * 40;
        int t = t0 - 17 + r;
        float e = 0.f;
        if (t >= 0 && t < TS) {
            float4 v = x4[((size_t)b * NN + (size_t)t * 160 + g * 4) >> 2];
            float m = 0.25f * (fabsf(v.x) + fabsf(v.y) + fabsf(v.z) + fabsf(v.w));
            e = __logf(m + EPS_LOG);
        }
        s_e[r * 72 + g] = (t >= 0 && t < TS) ? f2bf(e) : (unsigned short)0;
    }
    for (int idx = tid; idx < 65 * 24; idx += NTH) {
        int r = idx / 24, g = 40 + (idx - r * 24);
        s_e[r * 72 + g] = 0;
    }
    __syncthreads();   // bar 1: feat + e staged

    // =========== stage B: hid = leaky(conv1f + conv1t_eff); 2 cts x 4 time tiles ===========
#pragma unroll
    for (int ctp = 0; ctp < 2; ++ctp) {
        const int ct = wid * 2 + ctp;
        // per-ct weight load (L2-hot, amortized over 4 tiles)
        short8 wB0[6], wB1[6];
        {
            const unsigned short* bf0 = wu + W1F_U + ct * 2048 + lk * 128 + lr * 8;
            const unsigned short* bt0 = wu + W1T_U + ct * 1024 + lk * 128 + lr * 8;
#pragma unroll
            for (int s = 0; s < 4; ++s) {
                wB0[s] = *(const short8*)(bf0 + s * 512);
                wB1[s] = *(const short8*)(bf0 + 20480 + s * 512);
            }
#pragma unroll
            for (int s = 0; s < 2; ++s) {
                wB0[4 + s] = *(const short8*)(bt0 + s * 512);
                wB1[4 + s] = *(const short8*)(bt0 + 10240 + s * 512);
            }
        }
        const float bias1 = wf[B1C_F + ct * 16 + lr];
#pragma unroll 2
        for (int tile = 0; tile < 4; ++tile) {
            const int h0 = tile * 16;
            const unsigned short* f0 = &s_feat[(h0 + lr) * 136 + cbase];
            const unsigned short* e0 = &s_e[(h0 + lr) * 72 + cbase];
            f32x4 acc0 = {0.f, 0.f, 0.f, 0.f};
            f32x4 acc1 = {0.f, 0.f, 0.f, 0.f};
#pragma unroll
            for (int s = 0; s < 4; ++s) {
                short8 a0 = *(const short8*)(f0 + 32 * s);          // feat[t-1]
                short8 a1 = *(const short8*)(f0 + 136 + 32 * s);    // feat[t]
                acc0 = __builtin_amdgcn_mfma_f32_16x16x32_bf16(a0, wB0[s], acc0, 0, 0, 0);
                acc1 = __builtin_amdgcn_mfma_f32_16x16x32_bf16(a1, wB1[s], acc1, 0, 0, 0);
            }
#pragma unroll
            for (int s = 0; s < 2; ++s) {
                short8 a0 = *(const short8*)(e0 + 32 * s);
                short8 a1 = *(const short8*)(e0 + 72 + 32 * s);
                acc0 = __builtin_amdgcn_mfma_f32_16x16x32_bf16(a0, wB0[4 + s], acc0, 0, 0, 0);
                acc1 = __builtin_amdgcn_mfma_f32_16x16x32_bf16(a1, wB1[4 + s], acc1, 0, 0, 0);
            }
#pragma unroll
            for (int j = 0; j < 4; ++j) {
                int h  = h0 + lk * 4 + j;
                int th = t0 - 16 + h;
                float v = acc0[j] + acc1[j] + bias1;
                v = v >= 0.f ? v : 0.2f * v;
                s_hid[h * 168 + ct * 16 + lr] = (th >= 0) ? f2bf(v) : (unsigned short)0;
            }
        }
    }
    __syncthreads();   // bar 2: hid ready

    // =========== stage C: out = exp(conv2(hid)+b2)*x; 2 cts x 3 time tiles ===========
#pragma unroll
    for (int ctp = 0; ctp < 2; ++ctp) {
        const int ct = wid * 2 + ctp;
        short8 wC0[5], wC1[5];
        {
            const unsigned short* b2p = wu + W2_U + ct * 2560 + lk * 128 + lr * 8;
#pragma unroll
            for (int s = 0; s < 5; ++s) {
                wC0[s] = *(const short8*)(b2p + s * 512);
                wC1[s] = *(const short8*)(b2p + 25600 + s * 512);
            }
        }
        const float bias2 = wf[B2C_F + ct * 16 + lr];
#pragma unroll
        for (int tile = 0; tile < 3; ++tile) {
            const unsigned short* hb = &s_hid[(15 + tile * 16 + lr) * 168 + cbase];
            f32x4 acc0 = {0.f, 0.f, 0.f, 0.f};
            f32x4 acc1 = {0.f, 0.f, 0.f, 0.f};
#pragma unroll
            for (int s = 0; s < 5; ++s) {
                short8 a0 = *(const short8*)(hb + 32 * s);          // hid[t-1]
                short8 a1 = *(const short8*)(hb + 168 + 32 * s);    // hid[t]
                acc0 = __builtin_amdgcn_mfma_f32_16x16x32_bf16(a0, wC0[s], acc0, 0, 0, 0);
                acc1 = __builtin_amdgcn_mfma_f32_16x16x32_bf16(a1, wC1[s], acc1, 0, 0, 0);
            }
#pragma unroll
            for (int j = 0; j < 4; ++j) {
                int t = t0 + tile * 16 + lk * 4 + j;
                if (t < TS) {
                    size_t off = (size_t)b * NN + (size_t)t * 160 + ct * 16 + lr;
                    out[off] = __expf(acc0[j] + acc1[j] + bias2) * x[off];
                }
            }
        }
    }
}

extern "C" void kernel_launch(void* const* d_in, const int* in_sizes, int n_in,
                              void* d_out, int out_size, void* d_ws, size_t ws_size,
                              hipStream_t stream) {
    const float* x    = (const float*)d_in[0];
    const float* feat = (const float*)d_in[1];
    const float* W1f  = (const float*)d_in[2];
    const float* b1f  = (const float*)d_in[3];
    const float* W1t  = (const float*)d_in[4];
    const float* b1t  = (const float*)d_in[5];
    const float* W2   = (const float*)d_in[6];
    const float* b2   = (const float*)d_in[7];
    float* out = (float*)d_out;

    repack<<<(112960 + 255) / 256, 256, 0, stream>>>(W1f, b1f, W1t, b1t, W2, b2, d_ws);
    td_main<<<dim3(TB, BB), NTH, 0, stream>>>(
        x, feat, (const unsigned short*)d_ws, (const float*)d_ws, out);
}